// Round 1
// baseline (145.683 us; speedup 1.0000x reference)
//
#include <hip/hip_runtime.h>

namespace {
constexpr int CIN = 64, COUT = 64, SS = 1024;
constexpr int OT  = 8;    // o per block
constexpr int STL = 16;   // s per block
constexpr int CCH = 32;   // c per LDS chunk (2 chunks)
constexpr int POS = STL + 2;   // 18 s-positions incl. halo
constexpr int RST = 20;        // row stride in floats (16 b + 4 pad -> conflict-free-ish)
}

// Each thread: one s, two o's, all 16 b in registers (32 accumulators).
// Weight read exactly once globally; input broadcast via LDS (b-contiguous, b128 reads).
__global__ __launch_bounds__(64, 1)
void locon1d(const float* __restrict__ in, const float* __restrict__ wt,
             const float* __restrict__ bias, float* __restrict__ out) {
  __shared__ float xs[CCH * POS * RST];  // 45 KB

  const int tid = threadIdx.x;
  const int sl  = tid & 15;       // s within tile
  const int op  = tid >> 4;       // o-pair index 0..3
  const int bid = blockIdx.x;
  const int st  = bid & 63;       // 64 s-tiles
  const int ot  = bid >> 6;       // 8 o-tiles
  const int s0  = st * STL;
  const int o0  = ot * OT + op * 2;
  const int s   = s0 + sl;

  float acc[2][16];
  #pragma unroll
  for (int oo = 0; oo < 2; ++oo)
    #pragma unroll
    for (int b = 0; b < 16; ++b) acc[oo][b] = 0.f;

  // weight base pointers for the two o's at (o, c=0, s, k=0); layout (Cout,Cin,S,K)
  const float* wp0 = wt + ((size_t)(o0 + 0) * CIN * SS + s) * 3;
  const float* wp1 = wt + ((size_t)(o0 + 1) * CIN * SS + s) * 3;

  for (int ch = 0; ch < 2; ++ch) {
    const int cb = ch * CCH;

    // ---- stage input chunk into LDS: xs[c][pos][b], float4 along b ----
    {
      const int g  = tid & 3;     // b-group (4 b's)
      const int j0 = tid >> 2;    // 0..15 over (c,pos) cells
      #pragma unroll
      for (int i = 0; i < 36; ++i) {
        const int j = j0 + i * 16;          // 0..575 = 32c * 18pos
        const int c = j / POS;
        const int p = j - c * POS;
        const int sg = s0 - 1 + p;
        const bool v = (unsigned)sg < (unsigned)SS;
        const float* ip = in + ((size_t)(4 * g) * CIN + (cb + c)) * SS + sg;
        float4 x4;
        x4.x = v ? ip[0] : 0.f;
        x4.y = v ? ip[(size_t)1 * CIN * SS] : 0.f;
        x4.z = v ? ip[(size_t)2 * CIN * SS] : 0.f;
        x4.w = v ? ip[(size_t)3 * CIN * SS] : 0.f;
        *reinterpret_cast<float4*>(&xs[(c * POS + p) * RST + 4 * g]) = x4;
      }
    }
    __syncthreads();

    // ---- compute over this chunk; weight prefetched one 4-c group ahead ----
    constexpr int G = 4;
    float wr[2][G][2][3];   // [buf][c-in-group][o][k]
    auto loadw = [&](int ca, int buf, int u) {
      const float* p0 = wp0 + (size_t)ca * (SS * 3);
      const float* p1 = wp1 + (size_t)ca * (SS * 3);
      #pragma unroll
      for (int k = 0; k < 3; ++k) { wr[buf][u][0][k] = p0[k]; wr[buf][u][1][k] = p1[k]; }
    };

    #pragma unroll
    for (int u = 0; u < G; ++u) loadw(cb + u, 0, u);

    #pragma unroll
    for (int grp = 0; grp < CCH / G; ++grp) {
      const int buf = grp & 1;
      if (grp + 1 < CCH / G) {
        #pragma unroll
        for (int u = 0; u < G; ++u) loadw(cb + (grp + 1) * G + u, buf ^ 1, u);
      }
      #pragma unroll
      for (int u = 0; u < G; ++u) {
        const int cc = grp * G + u;
        const float* base = &xs[(cc * POS + sl) * RST];
        #pragma unroll
        for (int k = 0; k < 3; ++k) {
          #pragma unroll
          for (int g4 = 0; g4 < 4; ++g4) {
            const float4 x4 =
                *reinterpret_cast<const float4*>(base + k * RST + 4 * g4);
            #pragma unroll
            for (int oo = 0; oo < 2; ++oo) {
              const float w = wr[buf][u][oo][k];
              acc[oo][4 * g4 + 0] += w * x4.x;
              acc[oo][4 * g4 + 1] += w * x4.y;
              acc[oo][4 * g4 + 2] += w * x4.z;
              acc[oo][4 * g4 + 3] += w * x4.w;
            }
          }
        }
      }
    }
    __syncthreads();
  }

  // ---- epilogue: add bias, store coalesced over s ----
  #pragma unroll
  for (int oo = 0; oo < 2; ++oo) {
    const int o = o0 + oo;
    const float bz = bias[o * SS + s];
    #pragma unroll
    for (int b = 0; b < 16; ++b) {
      out[((size_t)b * COUT + o) * SS + s] = acc[oo][b] + bz;
    }
  }
}

extern "C" void kernel_launch(void* const* d_in, const int* in_sizes, int n_in,
                              void* d_out, int out_size, void* d_ws, size_t ws_size,
                              hipStream_t stream) {
  const float* in = (const float*)d_in[0];
  const float* wt = (const float*)d_in[1];
  const float* bs = (const float*)d_in[2];
  float* out = (float*)d_out;
  // grid: 64 s-tiles * 8 o-tiles = 512 blocks of 1 wave (~2 waves/CU, LDS 45KB/block)
  hipLaunchKernelGGL(locon1d, dim3(512), dim3(64), 0, stream, in, wt, bs, out);
}

// Round 2
// 117.693 us; speedup vs baseline: 1.2378x; 1.2378x over previous
//
#include <hip/hip_runtime.h>

namespace {
constexpr int CIN = 64, COUT = 64, SS = 1024, KK = 3;
constexpr int STL = 16;          // s per tile
constexpr int CCH = 8;           // c per chunk (8 chunks, split across blocks)
constexpr int POS = STL + 2;     // halo positions
constexpr int RST = 20;          // LDS row stride (floats): 16 b + 4 pad -> <=2-way banks
}

// Block = 256 threads = 16 s-lanes x 16 o-groups (4 o each). One c-chunk per block.
// Each thread: 1 s, 4 o, all 16 b in registers. Weights read exactly once globally.
// Cross-chunk reduction: global atomicAdd (out pre-zeroed by memsetAsync; chunk 0 adds bias).
__global__ __launch_bounds__(256, 2)
void locon1d(const float* __restrict__ in, const float* __restrict__ wt,
             const float* __restrict__ bias, float* __restrict__ out) {
  __shared__ float xs[CCH * POS * RST];  // 11.5 KB

  const int tid = threadIdx.x;
  const int sl  = tid & 15;        // s within tile
  const int og  = tid >> 4;        // 0..15 -> o base og*4
  const int bid = blockIdx.x;
  const int st  = bid & 63;        // 64 s-tiles
  const int ch  = bid >> 6;        // 8 c-chunks
  const int s0  = st * STL;
  const int s   = s0 + sl;
  const int cb  = ch * CCH;
  const int o0  = og * 4;

  // ---- stage input chunk into LDS: xs[c][pos][b] (float4 along b) ----
  #pragma unroll
  for (int i = 0; i < 3; ++i) {
    const int idx = tid + i * 256;           // cells: (c*4+g)*18 + p, 576 total
    if (idx < CCH * 4 * POS) {
      const int cg = idx / POS;
      const int p  = idx - cg * POS;
      const int g  = cg & 3;
      const int c  = cg >> 2;
      const int sg = s0 - 1 + p;
      const bool v = (unsigned)sg < (unsigned)SS;
      const float* ip = in + (size_t)(4 * g) * CIN * SS + (size_t)(cb + c) * SS + sg;
      float4 x4;
      x4.x = v ? ip[0] : 0.f;
      x4.y = v ? ip[(size_t)1 * CIN * SS] : 0.f;
      x4.z = v ? ip[(size_t)2 * CIN * SS] : 0.f;
      x4.w = v ? ip[(size_t)3 * CIN * SS] : 0.f;
      *reinterpret_cast<float4*>(&xs[(c * POS + p) * RST + 4 * g]) = x4;
    }
  }

  // ---- load ALL chunk weights into registers (96 floats/thread, max load ILP) ----
  float w[CCH][4][KK];
  #pragma unroll
  for (int oo = 0; oo < 4; ++oo) {
    const float* wp = wt + (((size_t)(o0 + oo) * CIN + cb) * SS + s) * KK;
    #pragma unroll
    for (int c = 0; c < CCH; ++c) {
      #pragma unroll
      for (int k = 0; k < KK; ++k) w[c][oo][k] = wp[(size_t)c * SS * KK + k];
    }
  }

  // ---- accumulators; chunk 0 folds in the bias ----
  float acc[4][16];
  #pragma unroll
  for (int oo = 0; oo < 4; ++oo) {
    const float bz = (ch == 0) ? bias[(o0 + oo) * SS + s] : 0.f;
    #pragma unroll
    for (int b = 0; b < 16; ++b) acc[oo][b] = bz;
  }

  __syncthreads();

  // ---- compute: 8c x 3k x 16b x 4o FMAs; b128 LDS reads broadcast across og lanes ----
  #pragma unroll
  for (int c = 0; c < CCH; ++c) {
    const float* base = &xs[(c * POS + sl) * RST];
    #pragma unroll
    for (int k = 0; k < KK; ++k) {
      #pragma unroll
      for (int g4 = 0; g4 < 4; ++g4) {
        const float4 x4 = *reinterpret_cast<const float4*>(base + k * RST + 4 * g4);
        #pragma unroll
        for (int oo = 0; oo < 4; ++oo) {
          const float wv = w[c][oo][k];
          acc[oo][4 * g4 + 0] += wv * x4.x;
          acc[oo][4 * g4 + 1] += wv * x4.y;
          acc[oo][4 * g4 + 2] += wv * x4.z;
          acc[oo][4 * g4 + 3] += wv * x4.w;
        }
      }
    }
  }

  // ---- reduce across c-chunks via atomics (out pre-zeroed each launch) ----
  #pragma unroll
  for (int oo = 0; oo < 4; ++oo) {
    const int o = o0 + oo;
    #pragma unroll
    for (int b = 0; b < 16; ++b) {
      atomicAdd(&out[((size_t)b * COUT + o) * SS + s], acc[oo][b]);
    }
  }
}

extern "C" void kernel_launch(void* const* d_in, const int* in_sizes, int n_in,
                              void* d_out, int out_size, void* d_ws, size_t ws_size,
                              hipStream_t stream) {
  const float* in = (const float*)d_in[0];
  const float* wt = (const float*)d_in[1];
  const float* bs = (const float*)d_in[2];
  float* out = (float*)d_out;
  hipMemsetAsync(out, 0, (size_t)out_size * sizeof(float), stream);
  // 64 s-tiles x 8 c-chunks = 512 blocks x 4 waves = 2048 waves (~8 waves/CU)
  hipLaunchKernelGGL(locon1d, dim3(512), dim3(256), 0, stream, in, wt, bs, out);
}

// Round 3
// 116.810 us; speedup vs baseline: 1.2472x; 1.0076x over previous
//
#include <hip/hip_runtime.h>

namespace {
constexpr int CIN = 64, COUT = 64, SS = 1024, KK = 3;
constexpr int STL = 4;            // s per block
constexpr int POS = STL + 2;      // 6 halo positions
constexpr int NCG = 8, CPG = 8;   // 8 c-groups of 8 channels (one wave each)
}

// Block = 512 threads = 8 waves. Thread (sl 0..3, og 0..15 -> 4 o's, cg 0..7 -> 8 c's).
// Full Cin*K reduction in-block (LDS tree over cg) -> NO global atomics.
// Weights: all 96 dwords/thread preloaded AFTER the staging barrier -> 96 loads in
// flight, FMA stream paced by HBM returns (no depth-1 load->use chain).
__global__ __launch_bounds__(512, 2)
void locon1d(const float* __restrict__ in, const float* __restrict__ wt,
             const float* __restrict__ bias, float* __restrict__ out) {
  __shared__ float smem[8192];  // 32 KB: xs uses 6144 floats; reused as partial buffer

  const int tid = threadIdx.x;
  const int sl  = tid & 3;
  const int og  = (tid >> 2) & 15;
  const int cg  = tid >> 6;           // == wave id
  const int bid = blockIdx.x;
  // XCD swizzle: st quads {4q..4q+3} land on one XCD -> output 64B lines merge in L2
  const int st  = ((bid & 7) << 5) + (bid >> 3);
  const int s0  = st * STL;
  const int s   = s0 + sl;
  const int o0  = og * 4;
  const int cb  = cg * CPG;

  // ---- stage input tile to LDS: xs[c][p][b], 64c x 6pos x 16b (24 KB) ----
  #pragma unroll
  for (int i = 0; i < 3; ++i) {
    const int t  = tid + i * 512;        // 0..1535 = 64c * 6p * 4bq
    const int c  = t / 24;
    const int r  = t - c * 24;
    const int bq = r / 6;
    const int p  = r - bq * 6;
    const int sg = s0 - 1 + p;
    const bool v = (unsigned)sg < (unsigned)SS;
    const float* ip = in + ((size_t)(4 * bq) * CIN + c) * SS + sg;
    float4 x4;
    x4.x = v ? ip[0] : 0.f;
    x4.y = v ? ip[(size_t)1 * CIN * SS] : 0.f;
    x4.z = v ? ip[(size_t)2 * CIN * SS] : 0.f;
    x4.w = v ? ip[(size_t)3 * CIN * SS] : 0.f;
    *reinterpret_cast<float4*>(&smem[(c * POS + p) * 16 + 4 * bq]) = x4;
  }
  __syncthreads();

  // ---- weight preload (after barrier so the stream is never drained by it) ----
  float w[CPG][4][KK];   // 96 VGPRs
  #pragma unroll
  for (int oo = 0; oo < 4; ++oo) {
    const float* wp = wt + (((size_t)(o0 + oo) * CIN + cb) * SS + s) * KK;
    #pragma unroll
    for (int c = 0; c < CPG; ++c)
      #pragma unroll
      for (int k = 0; k < KK; ++k)
        w[c][oo][k] = wp[(size_t)c * SS * KK + k];
  }

  // ---- compute: 8c x 3k x 16b x 4o FMAs, LDS b128 reads (broadcast across og) ----
  float acc[4][16];
  #pragma unroll
  for (int oo = 0; oo < 4; ++oo)
    #pragma unroll
    for (int b = 0; b < 16; ++b) acc[oo][b] = 0.f;

  #pragma unroll
  for (int c = 0; c < CPG; ++c) {
    #pragma unroll
    for (int k = 0; k < KK; ++k) {
      const float* base = &smem[((cb + c) * POS + sl + k) * 16];
      #pragma unroll
      for (int g = 0; g < 4; ++g) {
        const float4 x4 = *reinterpret_cast<const float4*>(base + 4 * g);
        #pragma unroll
        for (int oo = 0; oo < 4; ++oo) {
          const float wv = w[c][oo][k];
          acc[oo][4 * g + 0] += wv * x4.x;
          acc[oo][4 * g + 1] += wv * x4.y;
          acc[oo][4 * g + 2] += wv * x4.z;
          acc[oo][4 * g + 3] += wv * x4.w;
        }
      }
    }
  }

  // ---- in-block reduction over cg (8 partials) + coalesced epilogue ----
  // buf[cg][ (b*16+og)*4 + sl ]: writes & reads are lane-consecutive (conflict-free)
  #pragma unroll 1
  for (int oo = 0; oo < 4; ++oo) {
    __syncthreads();                      // also guards xs-alias on first round
    #pragma unroll
    for (int b = 0; b < 16; ++b)
      smem[cg * 1024 + (b * 16 + og) * 4 + sl] = acc[oo][b];
    __syncthreads();
    #pragma unroll
    for (int i = 0; i < 2; ++i) {
      const int item = tid + i * 512;     // (b 0..15, og2 0..15, sl2 0..3)
      float sum = 0.f;
      #pragma unroll
      for (int g = 0; g < NCG; ++g) sum += smem[g * 1024 + item];
      const int b   = item >> 6;
      const int rem = item & 63;
      const int o   = (rem >> 2) * 4 + oo;
      const int s2  = s0 + (rem & 3);
      out[((size_t)b * COUT + o) * SS + s2] = sum + bias[o * SS + s2];
    }
  }
}

extern "C" void kernel_launch(void* const* d_in, const int* in_sizes, int n_in,
                              void* d_out, int out_size, void* d_ws, size_t ws_size,
                              hipStream_t stream) {
  const float* in = (const float*)d_in[0];
  const float* wt = (const float*)d_in[1];
  const float* bs = (const float*)d_in[2];
  float* out = (float*)d_out;
  // 256 s-tiles (4 s each), full o & c per block; 256 blocks x 8 waves = 8 waves/CU
  hipLaunchKernelGGL(locon1d, dim3(256), dim3(512), 0, stream, in, wt, bs, out);
}

// Round 4
// 99.784 us; speedup vs baseline: 1.4600x; 1.1706x over previous
//
#include <hip/hip_runtime.h>

namespace {
constexpr int CIN = 64, COUT = 64, SS = 1024, KK = 3;
constexpr int STL = 4;            // s per block
constexpr int POS = STL + 2;      // 6 halo positions
constexpr int NCG = 8, CPG = 8;   // 8 c-groups of 8 channels (one wave each)
}

// Block = 512 threads = 8 waves. Thread (sl 0..3, og 0..15 -> 4 o's, cg 0..7 -> 8 c's).
// Full Cin*K reduction in-block (LDS tree over cg) -> NO global atomics.
// CRITICAL: every array index is compile-time (fully unrolled loops) -- a runtime
// index into acc[][] demotes it to scratch (R3: +33.5 MB HBM writes, 44 us).
__global__ __launch_bounds__(512, 2)
void locon1d(const float* __restrict__ in, const float* __restrict__ wt,
             const float* __restrict__ bias, float* __restrict__ out) {
  __shared__ float smem[8192];  // 32 KB: xs uses 6144 floats; reused as partial buffer

  const int tid = threadIdx.x;
  const int sl  = tid & 3;
  const int og  = (tid >> 2) & 15;
  const int cg  = tid >> 6;           // == wave id
  const int bid = blockIdx.x;
  // XCD swizzle: adjacent s-tiles are bid,bid+8 -> same XCD -> output/weight lines merge in L2
  const int st  = ((bid & 7) << 5) + (bid >> 3);
  const int s0  = st * STL;
  const int s   = s0 + sl;
  const int o0  = og * 4;
  const int cb  = cg * CPG;

  // ---- stage input tile to LDS: xs[c][p][b], 64c x 6pos x 16b (24 KB) ----
  #pragma unroll
  for (int i = 0; i < 3; ++i) {
    const int t  = tid + i * 512;        // 0..1535 = 64c * 6p * 4bq
    const int c  = t / 24;
    const int r  = t - c * 24;
    const int bq = r / 6;
    const int p  = r - bq * 6;
    const int sg = s0 - 1 + p;
    const bool v = (unsigned)sg < (unsigned)SS;
    const float* ip = in + ((size_t)(4 * bq) * CIN + c) * SS + sg;
    float4 x4;
    x4.x = v ? ip[0] : 0.f;
    x4.y = v ? ip[(size_t)1 * CIN * SS] : 0.f;
    x4.z = v ? ip[(size_t)2 * CIN * SS] : 0.f;
    x4.w = v ? ip[(size_t)3 * CIN * SS] : 0.f;
    *reinterpret_cast<float4*>(&smem[(c * POS + p) * 16 + 4 * bq]) = x4;
  }
  __syncthreads();

  // ---- weight preload: all 96 dwords/thread issued here, uses far below ----
  float w[CPG][4][KK];   // 96 VGPRs, all indices compile-time
  #pragma unroll
  for (int oo = 0; oo < 4; ++oo) {
    const float* wp = wt + (((size_t)(o0 + oo) * CIN + cb) * SS + s) * KK;
    #pragma unroll
    for (int c = 0; c < CPG; ++c)
      #pragma unroll
      for (int k = 0; k < KK; ++k)
        w[c][oo][k] = wp[(size_t)c * SS * KK + k];
  }

  // ---- compute: 8c x 3k x 16b x 4o FMAs, LDS b128 reads (broadcast across og) ----
  float acc[4][16];
  #pragma unroll
  for (int oo = 0; oo < 4; ++oo)
    #pragma unroll
    for (int b = 0; b < 16; ++b) acc[oo][b] = 0.f;

  #pragma unroll
  for (int c = 0; c < CPG; ++c) {
    #pragma unroll
    for (int k = 0; k < KK; ++k) {
      const float* base = &smem[((cb + c) * POS + sl + k) * 16];
      #pragma unroll
      for (int g = 0; g < 4; ++g) {
        const float4 x4 = *reinterpret_cast<const float4*>(base + 4 * g);
        #pragma unroll
        for (int oo = 0; oo < 4; ++oo) {
          const float wv = w[c][oo][k];
          acc[oo][4 * g + 0] += wv * x4.x;
          acc[oo][4 * g + 1] += wv * x4.y;
          acc[oo][4 * g + 2] += wv * x4.z;
          acc[oo][4 * g + 3] += wv * x4.w;
        }
      }
    }
  }

  // ---- in-block reduction over cg (8 partials) + coalesced epilogue ----
  // FULLY UNROLLED over oo: acc/bank indices stay compile-time -> registers.
  #pragma unroll
  for (int oo = 0; oo < 4; ++oo) {
    __syncthreads();                      // round 0: also guards xs-alias
    #pragma unroll
    for (int b = 0; b < 16; ++b)
      smem[cg * 1024 + (b * 16 + og) * 4 + sl] = acc[oo][b];
    __syncthreads();
    #pragma unroll
    for (int i = 0; i < 2; ++i) {
      const int item = tid + i * 512;     // (b 0..15, og2 0..15, sl2 0..3)
      float sum = 0.f;
      #pragma unroll
      for (int g = 0; g < NCG; ++g) sum += smem[g * 1024 + item];
      const int b   = item >> 6;
      const int rem = item & 63;
      const int o   = (rem >> 2) * 4 + oo;
      const int s2  = s0 + (rem & 3);
      out[((size_t)b * COUT + o) * SS + s2] = sum + bias[o * SS + s2];
    }
  }
}

extern "C" void kernel_launch(void* const* d_in, const int* in_sizes, int n_in,
                              void* d_out, int out_size, void* d_ws, size_t ws_size,
                              hipStream_t stream) {
  const float* in = (const float*)d_in[0];
  const float* wt = (const float*)d_in[1];
  const float* bs = (const float*)d_in[2];
  float* out = (float*)d_out;
  // 256 s-tiles (4 s each), full o & c per block; 256 blocks x 8 waves
  hipLaunchKernelGGL(locon1d, dim3(256), dim3(512), 0, stream, in, wt, bs, out);
}